// Round 17
// baseline (3783.100 us; speedup 1.0000x reference)
//
#include <hip/hip_runtime.h>
#include <cstddef>

// WordEncoder: emb gather -> masked LSTM (T=1024) -> relu(h@Wd+bd)
// R17 = R16 with ONE change: the non-temporal out-store (HBM, ~1000cy ack)
// is moved AFTER the certificate bump. Previously the producer's vmcnt(0)
// drained pktA+pktB+outNT before bumping the cert -- putting an HBM write
// ack (with zero ordering requirements) on the cross-CU critical path for
// every consumer taking the miss path. Now the bump waits only on pktA (L2)
// + pktB (IC). Everything else identical to R16: 512 blocks = 16bg x 32ug,
// 2/CU; pk_fma GEMM; (tag|h) packets dual-published; optimistic load after
// x-GEMM; IC-certificate fallback with sticky downgrade; tags validate
// every value (placement-independent, replay-safe).

typedef unsigned int u32x4 __attribute__((ext_vector_type(4)));
typedef float f32x2 __attribute__((ext_vector_type(2)));
typedef float f32x4 __attribute__((ext_vector_type(4)));

constexpr int TLEN = 1024;
constexpr int EDIM = 128;
constexpr int UDIM = 256;
constexpr int DDIM = 256;

constexpr int NBG  = 16;   // batch groups (32 producer blocks each)
constexpr int BPB  = 8;    // batches per block
constexpr int UPB  = 8;    // units per block
constexpr int ZCOL = 32;   // z cols per block (4 gates x 8 units)
constexpr int HXROW = 432; // (384/32)*36 padded row
constexpr int ZROW = 36;   // 32 + 4 pad

__device__ unsigned long long g_pktA[2][128][256]; // XCD-local path (L2)
__device__ unsigned long long g_pktB[2][128][256]; // device-coherent mirror (IC)
__device__ unsigned           g_cnt[NBG][32];      // agent-scope certificates

__device__ __forceinline__ int pidx(int k) { return ((k >> 5) * 36) + (k & 31); }

__device__ __forceinline__ u32x4 pkt_load_ic(const unsigned long long* p) {
  u32x4 v;
  asm volatile("global_load_dwordx4 %0, %1, off sc0 sc1" : "=v"(v) : "v"(p));
  return v;
}
__device__ __forceinline__ u32x4 pkt_load_l2(const unsigned long long* p) {
  u32x4 v; // sc0: bypass L1, hit the XCD-coherent L2
  asm volatile("global_load_dwordx4 %0, %1, off sc0" : "=v"(v) : "v"(p));
  return v;
}
__device__ __forceinline__ unsigned cnt_load_ic(const unsigned* p) {
  unsigned v;
  asm volatile("global_load_dword %0, %1, off sc0 sc1" : "=v"(v) : "v"(p));
  asm volatile("s_waitcnt vmcnt(0)" : "+v"(v) :: "memory");
  return v;
}
#define PKT_WAIT4(a, b, c, d) \
  asm volatile("s_waitcnt vmcnt(0)" : "+v"(a), "+v"(b), "+v"(c), "+v"(d) :: "memory")
#define TAGS_OK() \
  ((p0[1] == want) & (p0[3] == want) & (p1[1] == want) & (p1[3] == want) & \
   (p2[1] == want) & (p2[3] == want) & (p3[1] == want) & (p3[3] == want))

// Packed dual-FMA: acc(pair) += broadcast(h2.lo or h2.hi) * w(pair).
#define PK_FMA_LO(acc, h2, wp)                                              \
  asm("v_pk_fma_f32 %0, %1, %2, %0 op_sel:[0,0,0] op_sel_hi:[0,1,1]"        \
      : "+v"(acc) : "v"(h2), "v"(wp))
#define PK_FMA_HI(acc, h2, wp)                                              \
  asm("v_pk_fma_f32 %0, %1, %2, %0 op_sel:[1,0,0] op_sel_hi:[1,1,1]"        \
      : "+v"(acc) : "v"(h2), "v"(wp))

// Sum across the 16-lane DPP row (ksl groups == DPP rows). Pure VALU pipe.
__device__ __forceinline__ float rowsum16(float v) {
  v += __int_as_float(
      __builtin_amdgcn_mov_dpp(__float_as_int(v), 0x121, 0xf, 0xf, true));
  v += __int_as_float(
      __builtin_amdgcn_mov_dpp(__float_as_int(v), 0x122, 0xf, 0xf, true));
  v += __int_as_float(
      __builtin_amdgcn_mov_dpp(__float_as_int(v), 0x124, 0xf, 0xf, true));
  v += __int_as_float(
      __builtin_amdgcn_mov_dpp(__float_as_int(v), 0x128, 0xf, 0xf, true));
  return v;
}

__global__ void we_init() {
  const int i = blockIdx.x * 256 + threadIdx.x;
  if (i < NBG * 32)
    __hip_atomic_store(&(&g_cnt[0][0])[i], 0u, __ATOMIC_RELAXED,
                       __HIP_MEMORY_SCOPE_AGENT);
}

__global__ __launch_bounds__(256, 2) void we_lstm(
    const int* __restrict__ tokens, const float* __restrict__ emb,
    const float* __restrict__ Wk, const float* __restrict__ Wr,
    const float* __restrict__ bz, float* __restrict__ out)
{
  __shared__ float hx[2][BPB][HXROW]; // parity-dbuf [h(256)|x(128)], padded
  __shared__ float zs[BPB][ZROW];     // reduced z (pre-bias)
  __shared__ float bias_s[ZCOL];

  const int tid = threadIdx.x;
  const int bid = blockIdx.x;
  // Group remap: a bg's 32 blocks share bid%8 (one XCD under round-robin);
  // co-resident pair (bid, bid+256) -> same CU, different bg.
  const int bg  = ((bid & 7) << 1) | ((bid >> 8) & 1);
  const int ug  = (bid >> 3) & 31;
  const int b0  = bg * BPB;
  const int u0  = ug * UPB;

  // GEMM decomposition: 256 = 2 row-halves x 8 col-quads x 16 k-slices;
  // 4 batch rows per thread. k = ksl*4 + i*64 + j ; i<4 h-part, i>=4 x-part.
  const int ksl = tid & 15;
  const int cq  = (tid >> 4) & 7;
  const int bh  = tid >> 7;

  // ---- prologue: weight slice as f32x2 pairs (24k x 4c per thread) ----
  f32x2 w2[48]; // [(i*4+j)*2 + p] = cols {4cq+2p, 4cq+2p+1} at k
#pragma unroll
  for (int i = 0; i < 6; ++i)
#pragma unroll
    for (int j = 0; j < 4; ++j) {
      const int k = ksl * 4 + i * 64 + j;
#pragma unroll
      for (int p = 0; p < 2; ++p) {
        f32x2 wp;
#pragma unroll
        for (int e = 0; e < 2; ++e) {
          const int c   = cq * 4 + p * 2 + e;
          const int col = ((c >> 3) << 8) + u0 + (c & 7);
          wp[e] = (k < UDIM) ? Wr[k * 1024 + col] : Wk[(k - UDIM) * 1024 + col];
        }
        w2[(i * 4 + j) * 2 + p] = wp;
      }
    }
  if (tid < ZCOL) bias_s[tid] = bz[((tid >> 3) << 8) + u0 + (tid & 7)];

  float creg = 0.f;
  const int gb = tid >> 3, gu = tid & 7;         // gates (tid<64)
  const int xb = tid >> 5, xe = (tid & 31) << 2; // x stage
  const int up = tid & 127, bq = (tid >> 7) * 4; // pkt stage

  bool use_local = true; // self-tuning exchange path (sticky downgrade)

  // ---- prefetch step 0 x and gate-token ----
  float4 xv = *(const float4*)&emb[(size_t)tokens[(b0 + xb) * TLEN] * EDIM + xe];
  int tk_g = (tid < 64) ? tokens[(b0 + gb) * TLEN] : 1;

  for (int it = 0; it < TLEN; ++it) {
    const int cur = it & 1;

    // ---- write prefetched x -> LDS ----
    *(float4*)&hx[cur][xb][pidx(UDIM + xe)] = xv;
    __syncthreads(); // X: x staged

    f32x2 acc2[4][2];
#pragma unroll
    for (int r = 0; r < 4; ++r) {
      acc2[r][0] = (f32x2)(0.f);
      acc2[r][1] = (f32x2)(0.f);
    }
    // ---- x-part GEMM (i=4,5), packed dual-FMA ----
#pragma unroll
    for (int i = 4; i < 6; ++i) {
      const int hoff = pidx(ksl * 4 + i * 64);
#pragma unroll
      for (int r = 0; r < 4; ++r) {
        const f32x4 hv = *(const f32x4*)&hx[cur][bh * 4 + r][hoff];
        const f32x2 hlo = __builtin_shufflevector(hv, hv, 0, 1);
        const f32x2 hhi = __builtin_shufflevector(hv, hv, 2, 3);
        PK_FMA_LO(acc2[r][0], hlo, w2[(i * 4 + 0) * 2 + 0]); // j=0 (h=hv.x)
        PK_FMA_LO(acc2[r][1], hlo, w2[(i * 4 + 0) * 2 + 1]);
        PK_FMA_HI(acc2[r][0], hlo, w2[(i * 4 + 1) * 2 + 0]); // j=1 (h=hv.y)
        PK_FMA_HI(acc2[r][1], hlo, w2[(i * 4 + 1) * 2 + 1]);
        PK_FMA_LO(acc2[r][0], hhi, w2[(i * 4 + 2) * 2 + 0]); // j=2 (h=hv.z)
        PK_FMA_LO(acc2[r][1], hhi, w2[(i * 4 + 2) * 2 + 1]);
        PK_FMA_HI(acc2[r][0], hhi, w2[(i * 4 + 3) * 2 + 0]); // j=3 (h=hv.w)
        PK_FMA_HI(acc2[r][1], hhi, w2[(i * 4 + 3) * 2 + 1]);
      }
    }

    // ---- optimistic early packet load (R8 fast path) ----
    u32x4 p0, p1, p2, p3;
    const unsigned want = (unsigned)it; // producer tag = step+1
    const int rp = (it + 1) & 1;        // == (it-1)&1
    if (it > 0) {
      if (use_local) {
        p0 = pkt_load_l2(&g_pktA[rp][b0 + bq + 0][2 * up]);
        p1 = pkt_load_l2(&g_pktA[rp][b0 + bq + 1][2 * up]);
        p2 = pkt_load_l2(&g_pktA[rp][b0 + bq + 2][2 * up]);
        p3 = pkt_load_l2(&g_pktA[rp][b0 + bq + 3][2 * up]);
      } else {
        p0 = pkt_load_ic(&g_pktB[rp][b0 + bq + 0][2 * up]);
        p1 = pkt_load_ic(&g_pktB[rp][b0 + bq + 1][2 * up]);
        p2 = pkt_load_ic(&g_pktB[rp][b0 + bq + 2][2 * up]);
        p3 = pkt_load_ic(&g_pktB[rp][b0 + bq + 3][2 * up]);
      }
    }

    // ---- prefetch next-step x / gate-token (completes under the wait) ----
    float4 xv_n;
    int tk_g_n = 1;
    if (it + 1 < TLEN) {
      const int tk_x = tokens[(b0 + xb) * TLEN + it + 1];
      xv_n = *(const float4*)&emb[(size_t)tk_x * EDIM + xe];
      if (tid < 64) tk_g_n = tokens[(b0 + gb) * TLEN + it + 1];
    }

    // ---- resolve: tags -> certificate spin -> reload -> sticky IC loop ----
    const int ho = pidx(2 * up);
    if (it > 0) {
      PKT_WAIT4(p0, p1, p2, p3);
      bool ok = TAGS_OK();
      if (!ok) {
        const unsigned wantc = 32u * (unsigned)it; // 1 bump/block/step
        while (cnt_load_ic(&g_cnt[bg][0]) < wantc)
          __builtin_amdgcn_s_sleep(1);
        if (use_local) { // certified: same-XCD pktA must now be fresh
          p0 = pkt_load_l2(&g_pktA[rp][b0 + bq + 0][2 * up]);
          p1 = pkt_load_l2(&g_pktA[rp][b0 + bq + 1][2 * up]);
          p2 = pkt_load_l2(&g_pktA[rp][b0 + bq + 2][2 * up]);
          p3 = pkt_load_l2(&g_pktA[rp][b0 + bq + 3][2 * up]);
          PKT_WAIT4(p0, p1, p2, p3);
          ok = TAGS_OK();
          if (!ok) use_local = false; // cross-XCD placement: downgrade
        }
        while (!ok) { // IC mirror always fresh post-certificate
          p0 = pkt_load_ic(&g_pktB[rp][b0 + bq + 0][2 * up]);
          p1 = pkt_load_ic(&g_pktB[rp][b0 + bq + 1][2 * up]);
          p2 = pkt_load_ic(&g_pktB[rp][b0 + bq + 2][2 * up]);
          p3 = pkt_load_ic(&g_pktB[rp][b0 + bq + 3][2 * up]);
          PKT_WAIT4(p0, p1, p2, p3);
          ok = TAGS_OK();
          if (!ok) __builtin_amdgcn_s_sleep(1);
        }
      }
      *(float2*)&hx[cur][bq + 0][ho] =
          make_float2(__uint_as_float(p0[0]), __uint_as_float(p0[2]));
      *(float2*)&hx[cur][bq + 1][ho] =
          make_float2(__uint_as_float(p1[0]), __uint_as_float(p1[2]));
      *(float2*)&hx[cur][bq + 2][ho] =
          make_float2(__uint_as_float(p2[0]), __uint_as_float(p2[2]));
      *(float2*)&hx[cur][bq + 3][ho] =
          make_float2(__uint_as_float(p3[0]), __uint_as_float(p3[2]));
    } else {
#pragma unroll
      for (int jj = 0; jj < 4; ++jj)
        *(float2*)&hx[cur][bq + jj][ho] = make_float2(0.f, 0.f);
    }
    __syncthreads(); // A: h staged

    // ---- h-part GEMM (i=0..3), packed dual-FMA ----
#pragma unroll
    for (int i = 0; i < 4; ++i) {
      const int hoff = pidx(ksl * 4 + i * 64);
#pragma unroll
      for (int r = 0; r < 4; ++r) {
        const f32x4 hv = *(const f32x4*)&hx[cur][bh * 4 + r][hoff];
        const f32x2 hlo = __builtin_shufflevector(hv, hv, 0, 1);
        const f32x2 hhi = __builtin_shufflevector(hv, hv, 2, 3);
        PK_FMA_LO(acc2[r][0], hlo, w2[(i * 4 + 0) * 2 + 0]);
        PK_FMA_LO(acc2[r][1], hlo, w2[(i * 4 + 0) * 2 + 1]);
        PK_FMA_HI(acc2[r][0], hlo, w2[(i * 4 + 1) * 2 + 0]);
        PK_FMA_HI(acc2[r][1], hlo, w2[(i * 4 + 1) * 2 + 1]);
        PK_FMA_LO(acc2[r][0], hhi, w2[(i * 4 + 2) * 2 + 0]);
        PK_FMA_LO(acc2[r][1], hhi, w2[(i * 4 + 2) * 2 + 1]);
        PK_FMA_HI(acc2[r][0], hhi, w2[(i * 4 + 3) * 2 + 0]);
        PK_FMA_HI(acc2[r][1], hhi, w2[(i * 4 + 3) * 2 + 1]);
      }
    }

    // hazard guard: inline-asm pk_fma defs feed DPP reads below.
    asm volatile("s_nop 1");

    // ---- k-reduce via DPP row_ror (VALU pipe; ksl groups == DPP rows) ----
#pragma unroll
    for (int r = 0; r < 4; ++r) {
      float a0 = acc2[r][0].x, a1 = acc2[r][0].y;
      float a2 = acc2[r][1].x, a3 = acc2[r][1].y;
      a0 = rowsum16(a0); a1 = rowsum16(a1);
      a2 = rowsum16(a2); a3 = rowsum16(a3);
      if (ksl == 0)
        *(float4*)&zs[bh * 4 + r][cq * 4] = make_float4(a0, a1, a2, a3);
    }
    __syncthreads(); // B: zs ready

    // ---- gates + publish + certificate bump (wave 0) ----
    if (tid < 64) {
      const float zi = zs[gb][gu]      + bias_s[gu];
      const float zf = zs[gb][8 + gu]  + bias_s[8 + gu];
      const float zg = zs[gb][16 + gu] + bias_s[16 + gu];
      const float zo = zs[gb][24 + gu] + bias_s[24 + gu];
      const float gi = 1.f / (1.f + __expf(-zi));
      const float gf = 1.f / (1.f + __expf(-zf));
      const float gg = 1.f - 2.f / (1.f + __expf(2.f * zg)); // tanh
      const float go = 1.f / (1.f + __expf(-zo));
      const float cn = gf * creg + gi * gg;
      const float th = 1.f - 2.f / (1.f + __expf(2.f * cn));
      const float hn = go * th;
      const bool msk = (tk_g != 0);
      const float hold = hx[cur][gb][pidx(u0 + gu)];
      const float h2 = msk ? hn : hold;
      creg = msk ? cn : creg;
      const unsigned long long pkt =
          ((unsigned long long)(unsigned)(it + 1) << 32) | __float_as_uint(h2);
      // dual publish: XCD-local L2 copy + device-coherent IC mirror
      __hip_atomic_store(&g_pktA[cur][b0 + gb][u0 + gu], pkt, __ATOMIC_RELAXED,
                         __HIP_MEMORY_SCOPE_WORKGROUP);
      __hip_atomic_store(&g_pktB[cur][b0 + gb][u0 + gu], pkt, __ATOMIC_RELAXED,
                         __HIP_MEMORY_SCOPE_AGENT);
      // certificate: wait ONLY for the packet stores (L2 + IC acks), bump,
      // THEN issue the HBM h-history store (no consumer ordering needed --
      // we_proj runs after kernel end). R16 had the NT store inside the
      // drain, putting its ~1000cy HBM ack on the miss-path critical path.
      asm volatile("s_waitcnt vmcnt(0)" ::: "memory");
      if (tid == 0)
        __hip_atomic_fetch_add(&g_cnt[bg][0], 1u, __ATOMIC_RELAXED,
                               __HIP_MEMORY_SCOPE_AGENT);
      __builtin_nontemporal_store(
          h2, &out[((size_t)(b0 + gb) * TLEN + it) * DDIM + u0 + gu]);
    }
    xv = xv_n;
    tk_g = tk_g_n;
    // no end barrier: step it+1 writes hx[1-cur]; zs rewritten only after
    // barrier A(it+1); cross-block ordering is tag+certificate-clocked.
  }
}

// y = relu(H @ Wd + bd), in place over d_out (h history -> y). 32 rows/block.
__global__ __launch_bounds__(256, 2) void we_proj(
    const float* __restrict__ Wd, const float* __restrict__ bd,
    float* __restrict__ out)
{
  __shared__ float hs[32][260];
  __shared__ float ws[32][260];
  __shared__ float bds[DDIM];

  const int tid = threadIdx.x;
  const size_t row0 = (size_t)blockIdx.x * 32;

#pragma unroll
  for (int j2 = 0; j2 < 8; ++j2) {
    const int idx = tid + j2 * 256;
    const int r = idx >> 6;
    const int cq = idx & 63;
    *(float4*)&hs[r][cq * 4] = *(const float4*)&out[(row0 + r) * DDIM + cq * 4];
  }
  bds[tid] = bd[tid];

  const int rg = tid >> 5;
  const int c0 = (tid & 31) * 8;
  float acc[4][8];
#pragma unroll
  for (int i = 0; i < 4; ++i)
#pragma unroll
    for (int c = 0; c < 8; ++c) acc[i][c] = 0.f;

  for (int kt = 0; kt < 8; ++kt) {
    __syncthreads();
#pragma unroll
    for (int j2 = 0; j2 < 8; ++j2) {
      const int idx = tid + j2 * 256;
      const int kk = idx >> 6;
      const int cq = idx & 63;
      *(float4*)&ws[kk][cq * 4] =
          *(const float4*)&Wd[(size_t)(kt * 32 + kk) * DDIM + cq * 4];
    }
    __syncthreads();
#pragma unroll
    for (int kk = 0; kk < 32; ++kk) {
      const float4 wv0 = *(const float4*)&ws[kk][c0];
      const float4 wv1 = *(const float4*)&ws[kk][c0 + 4];
#pragma unroll
      for (int i = 0; i < 4; ++i) {
        const float hval = hs[rg + i * 8][kt * 32 + kk];
        acc[i][0] += hval * wv0.x; acc[i][1] += hval * wv0.y;
        acc[i][2] += hval * wv0.z; acc[i][3] += hval * wv0.w;
        acc[i][4] += hval * wv1.x; acc[i][5] += hval * wv1.y;
        acc[i][6] += hval * wv1.z; acc[i][7] += hval * wv1.w;
      }
    }
  }
#pragma unroll
  for (int i = 0; i < 4; ++i) {
    float4 y0, y1;
    y0.x = fmaxf(acc[i][0] + bds[c0 + 0], 0.f);
    y0.y = fmaxf(acc[i][1] + bds[c0 + 1], 0.f);
    y0.z = fmaxf(acc[i][2] + bds[c0 + 2], 0.f);
    y0.w = fmaxf(acc[i][3] + bds[c0 + 3], 0.f);
    y1.x = fmaxf(acc[i][4] + bds[c0 + 4], 0.f);
    y1.y = fmaxf(acc[i][5] + bds[c0 + 5], 0.f);
    y1.z = fmaxf(acc[i][6] + bds[c0 + 6], 0.f);
    y1.w = fmaxf(acc[i][7] + bds[c0 + 7], 0.f);
    const size_t orow = (row0 + rg + i * 8) * DDIM;
    *(float4*)&out[orow + c0]     = y0;
    *(float4*)&out[orow + c0 + 4] = y1;
  }
}

extern "C" void kernel_launch(void* const* d_in, const int* in_sizes, int n_in,
                              void* d_out, int out_size, void* d_ws, size_t ws_size,
                              hipStream_t stream) {
  const int*   tokens = (const int*)d_in[0];
  const float* emb    = (const float*)d_in[1];
  const float* Wk     = (const float*)d_in[2];
  const float* Wr     = (const float*)d_in[3];
  const float* bz     = (const float*)d_in[4];
  const float* Wd     = (const float*)d_in[5];
  const float* bd     = (const float*)d_in[6];
  float* out = (float*)d_out;
  (void)in_sizes; (void)n_in; (void)out_size; (void)d_ws; (void)ws_size;
  hipLaunchKernelGGL(we_init, dim3(2), dim3(256), 0, stream);
  hipLaunchKernelGGL(we_lstm, dim3(512), dim3(256), 0, stream,
                     tokens, emb, Wk, Wr, bz, out);
  hipLaunchKernelGGL(we_proj, dim3(128 * TLEN / 32), dim3(256), 0, stream,
                     Wd, bd, out);
}

// Round 18
// 3545.256 us; speedup vs baseline: 1.0671x; 1.0671x over previous
//
#include <hip/hip_runtime.h>
#include <cstddef>

// WordEncoder: emb gather -> masked LSTM (T=1024) -> relu(h@Wd+bd)
// R18 = R16/R17 base + dependency-loop surgery:
//  (1) main loop unrolled x4 with int4-batched tokens (all token accesses
//      are static register fields -> the chained token->emb wait no longer
//      sits inside the packet-resolve window);
//  (2) packet loads issued LAST in the window (after the emb-gather issue,
//      right before PKT_WAIT4): the sample lands ~1000cy after the peers'
//      publish (> L2 visibility) -> first-try tag hits; exposed exchange
//      cost ~ one L2 round trip.
// Everything else identical to R17: 512 blocks = 16bg x 32ug, 2/CU; pk_fma
// GEMM; (tag|h) packets dual-published (workgroup->L2 + agent->IC);
// IC-certificate fallback with sticky downgrade; out NT-store after the
// cert bump. Tags validate every value (placement-independent, replay-safe).

typedef unsigned int u32x4 __attribute__((ext_vector_type(4)));
typedef float f32x2 __attribute__((ext_vector_type(2)));
typedef float f32x4 __attribute__((ext_vector_type(4)));

constexpr int TLEN = 1024;
constexpr int EDIM = 128;
constexpr int UDIM = 256;
constexpr int DDIM = 256;

constexpr int NBG  = 16;   // batch groups (32 producer blocks each)
constexpr int BPB  = 8;    // batches per block
constexpr int UPB  = 8;    // units per block
constexpr int ZCOL = 32;   // z cols per block (4 gates x 8 units)
constexpr int HXROW = 432; // (384/32)*36 padded row
constexpr int ZROW = 36;   // 32 + 4 pad

__device__ unsigned long long g_pktA[2][128][256]; // XCD-local path (L2)
__device__ unsigned long long g_pktB[2][128][256]; // device-coherent mirror (IC)
__device__ unsigned           g_cnt[NBG][32];      // agent-scope certificates

__device__ __forceinline__ int pidx(int k) { return ((k >> 5) * 36) + (k & 31); }

__device__ __forceinline__ u32x4 pkt_load_ic(const unsigned long long* p) {
  u32x4 v;
  asm volatile("global_load_dwordx4 %0, %1, off sc0 sc1" : "=v"(v) : "v"(p));
  return v;
}
__device__ __forceinline__ u32x4 pkt_load_l2(const unsigned long long* p) {
  u32x4 v; // sc0: bypass L1, hit the XCD-coherent L2
  asm volatile("global_load_dwordx4 %0, %1, off sc0" : "=v"(v) : "v"(p));
  return v;
}
__device__ __forceinline__ unsigned cnt_load_ic(const unsigned* p) {
  unsigned v;
  asm volatile("global_load_dword %0, %1, off sc0 sc1" : "=v"(v) : "v"(p));
  asm volatile("s_waitcnt vmcnt(0)" : "+v"(v) :: "memory");
  return v;
}
#define PKT_WAIT4(a, b, c, d) \
  asm volatile("s_waitcnt vmcnt(0)" : "+v"(a), "+v"(b), "+v"(c), "+v"(d) :: "memory")
#define TAGS_OK() \
  ((p0[1] == want) & (p0[3] == want) & (p1[1] == want) & (p1[3] == want) & \
   (p2[1] == want) & (p2[3] == want) & (p3[1] == want) & (p3[3] == want))

// Packed dual-FMA: acc(pair) += broadcast(h2.lo or h2.hi) * w(pair).
#define PK_FMA_LO(acc, h2, wp)                                              \
  asm("v_pk_fma_f32 %0, %1, %2, %0 op_sel:[0,0,0] op_sel_hi:[0,1,1]"        \
      : "+v"(acc) : "v"(h2), "v"(wp))
#define PK_FMA_HI(acc, h2, wp)                                              \
  asm("v_pk_fma_f32 %0, %1, %2, %0 op_sel:[1,0,0] op_sel_hi:[1,1,1]"        \
      : "+v"(acc) : "v"(h2), "v"(wp))

// Sum across the 16-lane DPP row (ksl groups == DPP rows). Pure VALU pipe.
__device__ __forceinline__ float rowsum16(float v) {
  v += __int_as_float(
      __builtin_amdgcn_mov_dpp(__float_as_int(v), 0x121, 0xf, 0xf, true));
  v += __int_as_float(
      __builtin_amdgcn_mov_dpp(__float_as_int(v), 0x122, 0xf, 0xf, true));
  v += __int_as_float(
      __builtin_amdgcn_mov_dpp(__float_as_int(v), 0x124, 0xf, 0xf, true));
  v += __int_as_float(
      __builtin_amdgcn_mov_dpp(__float_as_int(v), 0x128, 0xf, 0xf, true));
  return v;
}

__global__ void we_init() {
  const int i = blockIdx.x * 256 + threadIdx.x;
  if (i < NBG * 32)
    __hip_atomic_store(&(&g_cnt[0][0])[i], 0u, __ATOMIC_RELAXED,
                       __HIP_MEMORY_SCOPE_AGENT);
}

__global__ __launch_bounds__(256, 2) void we_lstm(
    const int* __restrict__ tokens, const float* __restrict__ emb,
    const float* __restrict__ Wk, const float* __restrict__ Wr,
    const float* __restrict__ bz, float* __restrict__ out)
{
  __shared__ float hx[2][BPB][HXROW]; // parity-dbuf [h(256)|x(128)], padded
  __shared__ float zs[BPB][ZROW];     // reduced z (pre-bias)
  __shared__ float bias_s[ZCOL];

  const int tid = threadIdx.x;
  const int bid = blockIdx.x;
  // Group remap: a bg's 32 blocks share bid%8 (one XCD under round-robin);
  // co-resident pair (bid, bid+256) -> same CU, different bg.
  const int bg  = ((bid & 7) << 1) | ((bid >> 8) & 1);
  const int ug  = (bid >> 3) & 31;
  const int b0  = bg * BPB;
  const int u0  = ug * UPB;

  // GEMM decomposition: 256 = 2 row-halves x 8 col-quads x 16 k-slices;
  // 4 batch rows per thread. k = ksl*4 + i*64 + j ; i<4 h-part, i>=4 x-part.
  const int ksl = tid & 15;
  const int cq  = (tid >> 4) & 7;
  const int bh  = tid >> 7;

  // ---- prologue: weight slice as f32x2 pairs (24k x 4c per thread) ----
  f32x2 w2[48];
#pragma unroll
  for (int i = 0; i < 6; ++i)
#pragma unroll
    for (int j = 0; j < 4; ++j) {
      const int k = ksl * 4 + i * 64 + j;
#pragma unroll
      for (int p = 0; p < 2; ++p) {
        f32x2 wp;
#pragma unroll
        for (int e = 0; e < 2; ++e) {
          const int c   = cq * 4 + p * 2 + e;
          const int col = ((c >> 3) << 8) + u0 + (c & 7);
          wp[e] = (k < UDIM) ? Wr[k * 1024 + col] : Wk[(k - UDIM) * 1024 + col];
        }
        w2[(i * 4 + j) * 2 + p] = wp;
      }
    }
  if (tid < ZCOL) bias_s[tid] = bz[((tid >> 3) << 8) + u0 + (tid & 7)];

  float creg = 0.f;
  const int gb = tid >> 3, gu = tid & 7;         // gates (tid<64)
  const int xb = tid >> 5, xe = (tid & 31) << 2; // x stage
  const int up = tid & 127, bq = (tid >> 7) * 4; // pkt stage

  bool use_local = true; // self-tuning exchange path (sticky downgrade)

  const int row_x = (b0 + xb) * TLEN;
  const int row_g = (b0 + gb) * TLEN; // valid only for tid<64

  // ---- token quads for steps 0..3 + x(0) prefetch ----
  int4 tcx = *(const int4*)&tokens[row_x];
  int4 tcg = (tid < 64) ? *(const int4*)&tokens[row_g] : make_int4(1, 1, 1, 1);
  float4 xv = *(const float4*)&emb[(size_t)tcx.x * EDIM + xe];

  u32x4 p0, p1, p2, p3;

  // One LSTM step. cur/rp are compile-time at every call site; tok_next is
  // the (in-register) token for x(it+1); tkg is this step's gate token.
  auto step = [&](const int it, const int cur, const int tok_next,
                  const int tkg) {
    // ---- write prefetched x -> LDS ----
    *(float4*)&hx[cur][xb][pidx(UDIM + xe)] = xv;
    __syncthreads(); // X: x staged

    f32x2 acc2[4][2];
#pragma unroll
    for (int r = 0; r < 4; ++r) {
      acc2[r][0] = (f32x2)(0.f);
      acc2[r][1] = (f32x2)(0.f);
    }
    // ---- x-part GEMM (i=4,5), packed dual-FMA ----
#pragma unroll
    for (int i = 4; i < 6; ++i) {
      const int hoff = pidx(ksl * 4 + i * 64);
#pragma unroll
      for (int r = 0; r < 4; ++r) {
        const f32x4 hv = *(const f32x4*)&hx[cur][bh * 4 + r][hoff];
        const f32x2 hlo = __builtin_shufflevector(hv, hv, 0, 1);
        const f32x2 hhi = __builtin_shufflevector(hv, hv, 2, 3);
        PK_FMA_LO(acc2[r][0], hlo, w2[(i * 4 + 0) * 2 + 0]);
        PK_FMA_LO(acc2[r][1], hlo, w2[(i * 4 + 0) * 2 + 1]);
        PK_FMA_HI(acc2[r][0], hlo, w2[(i * 4 + 1) * 2 + 0]);
        PK_FMA_HI(acc2[r][1], hlo, w2[(i * 4 + 1) * 2 + 1]);
        PK_FMA_LO(acc2[r][0], hhi, w2[(i * 4 + 2) * 2 + 0]);
        PK_FMA_LO(acc2[r][1], hhi, w2[(i * 4 + 2) * 2 + 1]);
        PK_FMA_HI(acc2[r][0], hhi, w2[(i * 4 + 3) * 2 + 0]);
        PK_FMA_HI(acc2[r][1], hhi, w2[(i * 4 + 3) * 2 + 1]);
      }
    }

    // ---- emb gather for x(it+1): register token, no dependent wait ----
    float4 xv_n;
    if (it + 1 < TLEN)
      xv_n = *(const float4*)&emb[(size_t)tok_next * EDIM + xe];

    // ---- LATE packet sample: issue right before the wait (aged publish) --
    const unsigned want = (unsigned)it; // producer tag = step+1
    const int rp = cur ^ 1;             // == (it-1)&1
    if (it > 0) {
      if (use_local) {
        p0 = pkt_load_l2(&g_pktA[rp][b0 + bq + 0][2 * up]);
        p1 = pkt_load_l2(&g_pktA[rp][b0 + bq + 1][2 * up]);
        p2 = pkt_load_l2(&g_pktA[rp][b0 + bq + 2][2 * up]);
        p3 = pkt_load_l2(&g_pktA[rp][b0 + bq + 3][2 * up]);
      } else {
        p0 = pkt_load_ic(&g_pktB[rp][b0 + bq + 0][2 * up]);
        p1 = pkt_load_ic(&g_pktB[rp][b0 + bq + 1][2 * up]);
        p2 = pkt_load_ic(&g_pktB[rp][b0 + bq + 2][2 * up]);
        p3 = pkt_load_ic(&g_pktB[rp][b0 + bq + 3][2 * up]);
      }
    }

    // ---- resolve: tags -> certificate spin -> reload -> sticky IC loop ----
    const int ho = pidx(2 * up);
    if (it > 0) {
      PKT_WAIT4(p0, p1, p2, p3);
      bool ok = TAGS_OK();
      if (!ok) {
        const unsigned wantc = 32u * (unsigned)it; // 1 bump/block/step
        while (cnt_load_ic(&g_cnt[bg][0]) < wantc)
          __builtin_amdgcn_s_sleep(1);
        if (use_local) { // certified: same-XCD pktA must now be fresh
          p0 = pkt_load_l2(&g_pktA[rp][b0 + bq + 0][2 * up]);
          p1 = pkt_load_l2(&g_pktA[rp][b0 + bq + 1][2 * up]);
          p2 = pkt_load_l2(&g_pktA[rp][b0 + bq + 2][2 * up]);
          p3 = pkt_load_l2(&g_pktA[rp][b0 + bq + 3][2 * up]);
          PKT_WAIT4(p0, p1, p2, p3);
          ok = TAGS_OK();
          if (!ok) use_local = false; // cross-XCD placement: downgrade
        }
        while (!ok) { // IC mirror always fresh post-certificate
          p0 = pkt_load_ic(&g_pktB[rp][b0 + bq + 0][2 * up]);
          p1 = pkt_load_ic(&g_pktB[rp][b0 + bq + 1][2 * up]);
          p2 = pkt_load_ic(&g_pktB[rp][b0 + bq + 2][2 * up]);
          p3 = pkt_load_ic(&g_pktB[rp][b0 + bq + 3][2 * up]);
          PKT_WAIT4(p0, p1, p2, p3);
          ok = TAGS_OK();
          if (!ok) __builtin_amdgcn_s_sleep(1);
        }
      }
      *(float2*)&hx[cur][bq + 0][ho] =
          make_float2(__uint_as_float(p0[0]), __uint_as_float(p0[2]));
      *(float2*)&hx[cur][bq + 1][ho] =
          make_float2(__uint_as_float(p1[0]), __uint_as_float(p1[2]));
      *(float2*)&hx[cur][bq + 2][ho] =
          make_float2(__uint_as_float(p2[0]), __uint_as_float(p2[2]));
      *(float2*)&hx[cur][bq + 3][ho] =
          make_float2(__uint_as_float(p3[0]), __uint_as_float(p3[2]));
    } else {
#pragma unroll
      for (int jj = 0; jj < 4; ++jj)
        *(float2*)&hx[cur][bq + jj][ho] = make_float2(0.f, 0.f);
    }
    __syncthreads(); // A: h staged

    // ---- h-part GEMM (i=0..3), packed dual-FMA ----
#pragma unroll
    for (int i = 0; i < 4; ++i) {
      const int hoff = pidx(ksl * 4 + i * 64);
#pragma unroll
      for (int r = 0; r < 4; ++r) {
        const f32x4 hv = *(const f32x4*)&hx[cur][bh * 4 + r][hoff];
        const f32x2 hlo = __builtin_shufflevector(hv, hv, 0, 1);
        const f32x2 hhi = __builtin_shufflevector(hv, hv, 2, 3);
        PK_FMA_LO(acc2[r][0], hlo, w2[(i * 4 + 0) * 2 + 0]);
        PK_FMA_LO(acc2[r][1], hlo, w2[(i * 4 + 0) * 2 + 1]);
        PK_FMA_HI(acc2[r][0], hlo, w2[(i * 4 + 1) * 2 + 0]);
        PK_FMA_HI(acc2[r][1], hlo, w2[(i * 4 + 1) * 2 + 1]);
        PK_FMA_LO(acc2[r][0], hhi, w2[(i * 4 + 2) * 2 + 0]);
        PK_FMA_LO(acc2[r][1], hhi, w2[(i * 4 + 2) * 2 + 1]);
        PK_FMA_HI(acc2[r][0], hhi, w2[(i * 4 + 3) * 2 + 0]);
        PK_FMA_HI(acc2[r][1], hhi, w2[(i * 4 + 3) * 2 + 1]);
      }
    }

    // hazard guard: inline-asm pk_fma defs feed DPP reads below.
    asm volatile("s_nop 1");

    // ---- k-reduce via DPP row_ror (VALU pipe; ksl groups == DPP rows) ----
#pragma unroll
    for (int r = 0; r < 4; ++r) {
      float a0 = acc2[r][0].x, a1 = acc2[r][0].y;
      float a2 = acc2[r][1].x, a3 = acc2[r][1].y;
      a0 = rowsum16(a0); a1 = rowsum16(a1);
      a2 = rowsum16(a2); a3 = rowsum16(a3);
      if (ksl == 0)
        *(float4*)&zs[bh * 4 + r][cq * 4] = make_float4(a0, a1, a2, a3);
    }
    __syncthreads(); // B: zs ready

    // ---- gates + publish + certificate bump (wave 0) ----
    if (tid < 64) {
      const float zi = zs[gb][gu]      + bias_s[gu];
      const float zf = zs[gb][8 + gu]  + bias_s[8 + gu];
      const float zg = zs[gb][16 + gu] + bias_s[16 + gu];
      const float zo = zs[gb][24 + gu] + bias_s[24 + gu];
      const float gi = 1.f / (1.f + __expf(-zi));
      const float gf = 1.f / (1.f + __expf(-zf));
      const float gg = 1.f - 2.f / (1.f + __expf(2.f * zg)); // tanh
      const float go = 1.f / (1.f + __expf(-zo));
      const float cn = gf * creg + gi * gg;
      const float th = 1.f - 2.f / (1.f + __expf(2.f * cn));
      const float hn = go * th;
      const bool msk = (tkg != 0);
      const float hold = hx[cur][gb][pidx(u0 + gu)];
      const float h2 = msk ? hn : hold;
      creg = msk ? cn : creg;
      const unsigned long long pkt =
          ((unsigned long long)(unsigned)(it + 1) << 32) | __float_as_uint(h2);
      __hip_atomic_store(&g_pktA[cur][b0 + gb][u0 + gu], pkt, __ATOMIC_RELAXED,
                         __HIP_MEMORY_SCOPE_WORKGROUP);
      __hip_atomic_store(&g_pktB[cur][b0 + gb][u0 + gu], pkt, __ATOMIC_RELAXED,
                         __HIP_MEMORY_SCOPE_AGENT);
      asm volatile("s_waitcnt vmcnt(0)" ::: "memory");
      if (tid == 0)
        __hip_atomic_fetch_add(&g_cnt[bg][0], 1u, __ATOMIC_RELAXED,
                               __HIP_MEMORY_SCOPE_AGENT);
      __builtin_nontemporal_store(
          h2, &out[((size_t)(b0 + gb) * TLEN + it) * DDIM + u0 + gu]);
    }
    xv = xv_n;
  };

  for (int itb = 0; itb < TLEN; itb += 4) {
    // refill next token quads (dependency-free; age under this quad's GEMMs)
    const int nb = (itb + 4 < TLEN) ? itb + 4 : itb;
    const int4 tnx = *(const int4*)&tokens[row_x + nb];
    const int4 tng = (tid < 64) ? *(const int4*)&tokens[row_g + nb]
                                : make_int4(1, 1, 1, 1);
    step(itb + 0, 0, tcx.y, tcg.x);
    step(itb + 1, 1, tcx.z, tcg.y);
    step(itb + 2, 0, tcx.w, tcg.z);
    step(itb + 3, 1, tnx.x, tcg.w);
    tcx = tnx;
    tcg = tng;
  }
}

// y = relu(H @ Wd + bd), in place over d_out (h history -> y). 32 rows/block.
__global__ __launch_bounds__(256, 2) void we_proj(
    const float* __restrict__ Wd, const float* __restrict__ bd,
    float* __restrict__ out)
{
  __shared__ float hs[32][260];
  __shared__ float ws[32][260];
  __shared__ float bds[DDIM];

  const int tid = threadIdx.x;
  const size_t row0 = (size_t)blockIdx.x * 32;

#pragma unroll
  for (int j2 = 0; j2 < 8; ++j2) {
    const int idx = tid + j2 * 256;
    const int r = idx >> 6;
    const int cq = idx & 63;
    *(float4*)&hs[r][cq * 4] = *(const float4*)&out[(row0 + r) * DDIM + cq * 4];
  }
  bds[tid] = bd[tid];

  const int rg = tid >> 5;
  const int c0 = (tid & 31) * 8;
  float acc[4][8];
#pragma unroll
  for (int i = 0; i < 4; ++i)
#pragma unroll
    for (int c = 0; c < 8; ++c) acc[i][c] = 0.f;

  for (int kt = 0; kt < 8; ++kt) {
    __syncthreads();
#pragma unroll
    for (int j2 = 0; j2 < 8; ++j2) {
      const int idx = tid + j2 * 256;
      const int kk = idx >> 6;
      const int cq = idx & 63;
      *(float4*)&ws[kk][cq * 4] =
          *(const float4*)&Wd[(size_t)(kt * 32 + kk) * DDIM + cq * 4];
    }
    __syncthreads();
#pragma unroll
    for (int kk = 0; kk < 32; ++kk) {
      const float4 wv0 = *(const float4*)&ws[kk][c0];
      const float4 wv1 = *(const float4*)&ws[kk][c0 + 4];
#pragma unroll
      for (int i = 0; i < 4; ++i) {
        const float hval = hs[rg + i * 8][kt * 32 + kk];
        acc[i][0] += hval * wv0.x; acc[i][1] += hval * wv0.y;
        acc[i][2] += hval * wv0.z; acc[i][3] += hval * wv0.w;
        acc[i][4] += hval * wv1.x; acc[i][5] += hval * wv1.y;
        acc[i][6] += hval * wv1.z; acc[i][7] += hval * wv1.w;
      }
    }
  }
#pragma unroll
  for (int i = 0; i < 4; ++i) {
    float4 y0, y1;
    y0.x = fmaxf(acc[i][0] + bds[c0 + 0], 0.f);
    y0.y = fmaxf(acc[i][1] + bds[c0 + 1], 0.f);
    y0.z = fmaxf(acc[i][2] + bds[c0 + 2], 0.f);
    y0.w = fmaxf(acc[i][3] + bds[c0 + 3], 0.f);
    y1.x = fmaxf(acc[i][4] + bds[c0 + 4], 0.f);
    y1.y = fmaxf(acc[i][5] + bds[c0 + 5], 0.f);
    y1.z = fmaxf(acc[i][6] + bds[c0 + 6], 0.f);
    y1.w = fmaxf(acc[i][7] + bds[c0 + 7], 0.f);
    const size_t orow = (row0 + rg + i * 8) * DDIM;
    *(float4*)&out[orow + c0]     = y0;
    *(float4*)&out[orow + c0 + 4] = y1;
  }
}

extern "C" void kernel_launch(void* const* d_in, const int* in_sizes, int n_in,
                              void* d_out, int out_size, void* d_ws, size_t ws_size,
                              hipStream_t stream) {
  const int*   tokens = (const int*)d_in[0];
  const float* emb    = (const float*)d_in[1];
  const float* Wk     = (const float*)d_in[2];
  const float* Wr     = (const float*)d_in[3];
  const float* bz     = (const float*)d_in[4];
  const float* Wd     = (const float*)d_in[5];
  const float* bd     = (const float*)d_in[6];
  float* out = (float*)d_out;
  (void)in_sizes; (void)n_in; (void)out_size; (void)d_ws; (void)ws_size;
  hipLaunchKernelGGL(we_init, dim3(2), dim3(256), 0, stream);
  hipLaunchKernelGGL(we_lstm, dim3(512), dim3(256), 0, stream,
                     tokens, emb, Wk, Wr, bz, out);
  hipLaunchKernelGGL(we_proj, dim3(128 * TLEN / 32), dim3(256), 0, stream,
                     Wd, bd, out);
}